// Round 10
// baseline (347.669 us; speedup 1.0000x reference)
//
#include <hip/hip_runtime.h>

#define DEV static __device__ __forceinline__

typedef __attribute__((ext_vector_type(8))) short bf16x8;
typedef __attribute__((ext_vector_type(4))) float f32x4;
typedef __attribute__((ext_vector_type(4))) unsigned u32x4;

constexpr int BB = 8, NN = 4096, KK = 64, DD = 256, GG = 512;
constexpr int PITCH = 560;   // bytes/row: 140 dwords, rot 12 banks/row -> cheap conflicts, additive addressing

DEV unsigned short f2b(float f){
  unsigned u = __builtin_bit_cast(unsigned, f);
  unsigned r = (u + 0x7FFFu + ((u >> 16) & 1u)) >> 16;
  return (unsigned short)r;
}
DEV float b2f(unsigned short h){
  unsigned u = ((unsigned)h) << 16;
  return __builtin_bit_cast(float, u);
}
// 1-op packed f32x2 -> bf16x2 (RNE).
DEV unsigned f2b2(float lo, float hi){
  unsigned r;
  asm("v_cvt_pk_bf16_f32 %0, %1, %2" : "=v"(r) : "v"(lo), "v"(hi));
  return r;
}
DEV int rof(int row, int byteoff){ return row*PITCH + byteoff; }

DEV f32x4 zero4(){ f32x4 z = {0.f, 0.f, 0.f, 0.f}; return z; }

// ---------------- dtype detector ----------------
__global__ void k_detect(const unsigned short* __restrict__ x_raw, int* __restrict__ flag){
  int lane = threadIdx.x;  // 64 threads
  float mx = 0.f;
#pragma unroll
  for (int i = 0; i < 16; ++i) mx = fmaxf(mx, fabsf(b2f(x_raw[lane*16 + i])));
  unsigned long long big = __ballot(mx > 1e4f);
  if (lane == 0) *flag = (big == 0ull) ? 1 : 0;
}

// ---------------- conversion of weights / xyz / biases ----------------
struct PrepArgs {
  const void* src[12];
  void*       dst[12];
  int         n[12];
  int         bf16out[12];
};

__global__ void k_prep(PrepArgs P, const int* __restrict__ flagp){
  int flag = *flagp;
  long stride = (long)gridDim.x * blockDim.x;
  long gid = (long)blockIdx.x * blockDim.x + threadIdx.x;
  for (int s = 0; s < 12; ++s){
    int ns = P.n[s];
    const void* sp = P.src[s];
    if (P.bf16out[s]){
      unsigned short* dp = (unsigned short*)P.dst[s];
      for (long i = gid; i < ns; i += stride)
        dp[i] = flag ? ((const unsigned short*)sp)[i] : f2b(((const float*)sp)[i]);
    } else {
      float* dp = (float*)P.dst[s];
      for (long i = gid; i < ns; i += stride)
        dp[i] = flag ? b2f(((const unsigned short*)sp)[i]) : ((const float*)sp)[i];
    }
  }
}

// Preload the first B-fragment pair of a 32-col GEMM.
DEV void preB(const unsigned short* __restrict__ Wt, int lane, int c0, bf16x8 b0[2]){
  const unsigned short* wbase = Wt + (c0 + (lane & 15))*DD + (lane >> 4)*8;
  b0[0] = *(const bf16x8*)(wbase);
  b0[1] = *(const bf16x8*)(wbase + 16*DD);
}

// ---------------- 64x256 @ (64-col slice of W)^T, per-wave 64x64 (k_gemmA) ----------------
DEV void gemm64(const char* sbuf, const unsigned short* __restrict__ Wt,
                int lane, int c0, f32x4 acc[4][4]){
  const int lrow = lane & 15, lk = lane >> 4;
  const unsigned short* wbase = Wt + (c0 + lrow)*DD + lk*8;
  bf16x8 bcur[4], bnxt[4];
#pragma unroll
  for (int nf = 0; nf < 4; ++nf) bcur[nf] = *(const bf16x8*)(wbase + nf*16*DD);
#pragma unroll
  for (int ks = 0; ks < 8; ++ks){
    bf16x8 a[4];
#pragma unroll
    for (int mf = 0; mf < 4; ++mf)
      a[mf] = *(const bf16x8*)(sbuf + rof(mf*16 + lrow, ks*64 + lk*16));
    if (ks < 7){
#pragma unroll
      for (int nf = 0; nf < 4; ++nf)
        bnxt[nf] = *(const bf16x8*)(wbase + nf*16*DD + (ks + 1)*32);
    }
    __builtin_amdgcn_s_setprio(1);
#pragma unroll
    for (int mf = 0; mf < 4; ++mf)
#pragma unroll
      for (int nf = 0; nf < 4; ++nf)
        acc[mf][nf] = __builtin_amdgcn_mfma_f32_16x16x32_bf16(a[mf], bcur[nf], acc[mf][nf], 0, 0, 0);
    __builtin_amdgcn_s_setprio(0);
#pragma unroll
    for (int nf = 0; nf < 4; ++nf) bcur[nf] = bnxt[nf];
  }
}

// ---------------- 64x256 @ (32-col slice of W)^T, per-wave 64x32 (k_attn) ----------------
DEV void gemm32(const char* sbuf, const unsigned short* __restrict__ Wt,
                int lane, int c0, f32x4 acc[4][2], const bf16x8 b0[2]){
  const int lrow = lane & 15, lk = lane >> 4;
  const unsigned short* wbase = Wt + (c0 + lrow)*DD + lk*8;
  bf16x8 bcur[2], bnxt[2];
  bcur[0] = b0[0]; bcur[1] = b0[1];
#pragma unroll
  for (int ks = 0; ks < 8; ++ks){
    bf16x8 a[4];
#pragma unroll
    for (int mf = 0; mf < 4; ++mf)
      a[mf] = *(const bf16x8*)(sbuf + rof(mf*16 + lrow, ks*64 + lk*16));
    if (ks < 7){
#pragma unroll
      for (int nf = 0; nf < 2; ++nf)
        bnxt[nf] = *(const bf16x8*)(wbase + nf*16*DD + (ks + 1)*32);
    }
    __builtin_amdgcn_s_setprio(1);
#pragma unroll
    for (int mf = 0; mf < 4; ++mf)
#pragma unroll
      for (int nf = 0; nf < 2; ++nf)
        acc[mf][nf] = __builtin_amdgcn_mfma_f32_16x16x32_bf16(a[mf], bcur[nf], acc[mf][nf], 0, 0, 0);
    __builtin_amdgcn_s_setprio(0);
#pragma unroll
    for (int nf = 0; nf < 2; ++nf) bcur[nf] = bnxt[nf];
  }
}

// ---------------- Phase A: k = x@Wk.T, v = x@Wv.T, gq = x[:, :G]@Wq.T ----------------
__global__ __launch_bounds__(256, 2) void k_gemmA(
    const void* __restrict__ x_in,
    const unsigned short* __restrict__ Wq_b, const unsigned short* __restrict__ Wk_b,
    const unsigned short* __restrict__ Wv_b,
    unsigned short* __restrict__ ktab, unsigned short* __restrict__ vtab,
    float* __restrict__ gq, const int* __restrict__ flagp){
  __shared__ __align__(16) char sA[64*PITCH];
  const int tid = threadIdx.x, lane = tid & 63, wv = tid >> 6;
  const int flag = *flagp;
  const long row0 = (long)blockIdx.x * 64;
  const int b = (int)(row0 >> 12), n0 = (int)(row0 & 4095);

#pragma unroll
  for (int it = 0; it < 8; ++it){
    int r = (tid >> 5) + it*8;
    int f0 = (tid & 31)*8;
    bf16x8 v;
    if (flag){
      v = *(const bf16x8*)((const unsigned short*)x_in + (row0 + r)*DD + f0);
    } else {
      const float* xp = (const float*)x_in + (row0 + r)*DD + f0;
      f32x4 lo = *(const f32x4*)xp;
      f32x4 hi = *(const f32x4*)(xp + 4);
      u32x4 t;
#pragma unroll
      for (int e = 0; e < 2; ++e){ t[e] = f2b2(lo[2*e], lo[2*e+1]); t[e+2] = f2b2(hi[2*e], hi[2*e+1]); }
      v = __builtin_bit_cast(bf16x8, t);
    }
    *(bf16x8*)(sA + rof(r, f0*2)) = v;
  }
  __syncthreads();

  const int c0 = wv*64;
  const int nout = (n0 < GG) ? 3 : 2;
  for (int o = 0; o < nout; ++o){
    const unsigned short* Wt = (o == 0) ? Wk_b : (o == 1) ? Wv_b : Wq_b;
    f32x4 acc[4][4];
#pragma unroll
    for (int mf = 0; mf < 4; ++mf)
#pragma unroll
      for (int nf = 0; nf < 4; ++nf) acc[mf][nf] = zero4();
    gemm64(sA, Wt, lane, c0, acc);
#pragma unroll
    for (int mf = 0; mf < 4; ++mf)
#pragma unroll
      for (int nf = 0; nf < 4; ++nf)
#pragma unroll
        for (int r = 0; r < 4; ++r){
          int grow = mf*16 + (lane >> 4)*4 + r;
          int col = c0 + nf*16 + (lane & 15);
          float v = acc[mf][nf][r];
          if (o == 0)      ktab[(row0 + grow)*DD + col] = f2b(v);
          else if (o == 1) vtab[(row0 + grow)*DD + col] = f2b(v);
          else             gq[((long)b*GG + n0 + grow)*DD + col] = v;
        }
  }
}

// ---------------- Phase B: fused per-group attention (512 threads / 8 waves) ----------------
// SINGLE LDS tile S (38.6 KB total) — pos lives in packed bf16 regs (pos_pk) for
// the wave's own cols + transiently in S for phase 3. Sigma w*pos folded into the
// softmax via shuffle-reduce (s_out); phase 7 is Sigma w*v only.
// Target: 3 WGs/CU (24 waves, 66% occ) at <=85 VGPRs via __launch_bounds__(512,6).
__global__ __launch_bounds__(512, 6) void k_attn(
    const unsigned short* __restrict__ ktab, const unsigned short* __restrict__ vtab,
    const float* __restrict__ gq, const float* __restrict__ xyzf, const int* __restrict__ didx,
    const unsigned short* __restrict__ Wd2_b, const unsigned short* __restrict__ Wg1_b,
    const unsigned short* __restrict__ Wg2_b,
    const float* __restrict__ Wd1f, const float* __restrict__ bd1f, const float* __restrict__ bd2f,
    const float* __restrict__ bg1f, const float* __restrict__ bg2f,
    void* __restrict__ out, const int* __restrict__ flagp){
  __shared__ __align__(16) char S[64*PITCH];  // H1 -> pos -> a_in -> h2 -> w -> partials
  __shared__ float s_gq[256];
  __shared__ float s_delta[64*3];
  __shared__ float s_out[256];

  const int tid = threadIdx.x, lane = tid & 63, wv = tid >> 6;   // wv 0..7
  const int gang = tid >> 5;          // 0..15: rows gang*4 .. gang*4+3
  const int f0 = (tid & 31)*8;        // col start for row-phases
  const int flag = *flagp;
  int wg = blockIdx.x;
  wg = (wg & 7)*512 + (wg >> 3);      // XCD swizzle: batch-contiguous per XCD
  const int b = wg >> 9, g = wg & 511;
  const long bN = (long)b * NN;

  // ---- phase 0: indices, gq, delta; Wd1/bd1 -> registers; bg2 bias hoist ----
  int jrow[4];
  {
    const int* dptr = didx + (bN + g)*KK + gang*4;
#pragma unroll
    for (int it = 0; it < 4; ++it) jrow[it] = dptr[it];
  }
  if (tid < 256) s_gq[tid] = gq[((long)b*GG + g)*DD + tid];
  if (tid < 64){
    int j = didx[(bN + g)*KK + tid];
    long qb = (bN + g)*3, jb = (bN + j)*3;
#pragma unroll
    for (int c = 0; c < 3; ++c) s_delta[tid*3 + c] = xyzf[qb + c] - xyzf[jb + c];
  }
  f32x4 w1v[6];
  {
    const f32x4* wp = (const f32x4*)(Wd1f + f0*3);
#pragma unroll
    for (int q = 0; q < 6; ++q) w1v[q] = wp[q];
  }
  f32x4 b1lo = *(const f32x4*)(bd1f + f0), b1hi = *(const f32x4*)(bd1f + f0 + 4);
  const int c0 = wv*32;
  float bg2lo = bg2f[c0 + (lane & 15)];
  float bg2hi = bg2f[c0 + 16 + (lane & 15)];
  __syncthreads();                                   // #1

  // ---- phase 1: H1 = relu(delta @ Wd1.T + bd1) -> S ----
  bf16x8 b0d2[2];
  preB(Wd2_b, lane, c0, b0d2);
#pragma unroll
  for (int it = 0; it < 4; ++it){
    int r = gang*4 + it;
    float d0 = s_delta[r*3], d1 = s_delta[r*3+1], d2 = s_delta[r*3+2];
    float h[8];
#pragma unroll
    for (int e = 0; e < 8; ++e){
      float bias = (e < 4) ? b1lo[e] : b1hi[e-4];
      float w0 = w1v[(e*3+0) >> 2][(e*3+0) & 3];
      float w1 = w1v[(e*3+1) >> 2][(e*3+1) & 3];
      float w2 = w1v[(e*3+2) >> 2][(e*3+2) & 3];
      h[e] = fmaxf(fmaf(d0, w0, fmaf(d1, w1, fmaf(d2, w2, bias))), 0.f);
    }
    u32x4 t;
#pragma unroll
    for (int q = 0; q < 4; ++q) t[q] = f2b2(h[2*q], h[2*q+1]);
    *(bf16x8*)(S + rof(r, f0*2)) = __builtin_bit_cast(bf16x8, t);
  }

  // EARLY k-gather: in flight through GEMM1b, consumed in phase 3.
  bf16x8 kreg[4];
#pragma unroll
  for (int it = 0; it < 4; ++it)
    kreg[it] = *(const bf16x8*)(ktab + (bN + jrow[it])*DD + f0);
  __syncthreads();                                   // #2

  // ---- phase 2: pos = H1 @ Wd2.T + bd2 -> pos_pk regs AND bf16 into S ----
  unsigned pos_pk[4][2][2];
  {
    f32x4 acc[4][2];
#pragma unroll
    for (int mf = 0; mf < 4; ++mf)
#pragma unroll
      for (int nf = 0; nf < 2; ++nf) acc[mf][nf] = zero4();
    gemm32(S, Wd2_b, lane, c0, acc, b0d2);
    __syncthreads();                                 // #3 (all H1 reads done before S overwrite)
#pragma unroll
    for (int nf = 0; nf < 2; ++nf){
      float bias = bd2f[c0 + nf*16 + (lane & 15)];
#pragma unroll
      for (int mf = 0; mf < 4; ++mf){
        int row = mf*16 + (lane >> 4)*4;
        int col = c0 + nf*16 + (lane & 15);
#pragma unroll
        for (int h = 0; h < 2; ++h){
          unsigned pk = f2b2(acc[mf][nf][2*h] + bias, acc[mf][nf][2*h+1] + bias);
          pos_pk[mf][nf][h] = pk;
          *(unsigned short*)(S + rof(row + 2*h,     col*2)) = (unsigned short)(pk & 0xffff);
          *(unsigned short*)(S + rof(row + 2*h + 1, col*2)) = (unsigned short)(pk >> 16);
        }
      }
    }
  }
  __syncthreads();                                   // #4 (pos visible)

  // ---- phase 3: a_in = gq - k + pos, IN PLACE in S; prefetch Wg1 b0 ----
  bf16x8 b0g1[2];
  preB(Wg1_b, lane, c0, b0g1);
#pragma unroll
  for (int it = 0; it < 4; ++it){
    int r = gang*4 + it;
    bf16x8 p8 = *(const bf16x8*)(S + rof(r, f0*2));
    float v[8];
#pragma unroll
    for (int e = 0; e < 8; ++e)
      v[e] = s_gq[f0 + e] - b2f((unsigned short)kreg[it][e]) + b2f((unsigned short)p8[e]);
    u32x4 t;
#pragma unroll
    for (int q = 0; q < 4; ++q) t[q] = f2b2(v[2*q], v[2*q+1]);
    *(bf16x8*)(S + rof(r, f0*2)) = __builtin_bit_cast(bf16x8, t);
  }
  __syncthreads();                                   // #5

  // ---- phase 4: h2 = relu(a_in @ Wg1.T + bg1) -> S; prefetch Wg2 b0 ----
  bf16x8 b0g2[2];
  {
    f32x4 acc[4][2];
#pragma unroll
    for (int mf = 0; mf < 4; ++mf)
#pragma unroll
      for (int nf = 0; nf < 2; ++nf) acc[mf][nf] = zero4();
    gemm32(S, Wg1_b, lane, c0, acc, b0g1);
    preB(Wg2_b, lane, c0, b0g2);
    __syncthreads();                                 // #6 (all a_in reads done)
#pragma unroll
    for (int nf = 0; nf < 2; ++nf){
      float bias = bg1f[c0 + nf*16 + (lane & 15)];
#pragma unroll
      for (int mf = 0; mf < 4; ++mf){
        int row = mf*16 + (lane >> 4)*4;
        int col = c0 + nf*16 + (lane & 15);
#pragma unroll
        for (int h = 0; h < 2; ++h){
          unsigned pk = f2b2(fmaxf(acc[mf][nf][2*h] + bias, 0.f),
                             fmaxf(acc[mf][nf][2*h+1] + bias, 0.f));
          *(unsigned short*)(S + rof(row + 2*h,     col*2)) = (unsigned short)(pk & 0xffff);
          *(unsigned short*)(S + rof(row + 2*h + 1, col*2)) = (unsigned short)(pk >> 16);
        }
      }
    }
  }
  __syncthreads();                                   // #7

  // ---- phase 5: logits = h2 @ Wg2.T + bg2 ----
  f32x4 lg[4][2];
#pragma unroll
  for (int mf = 0; mf < 4; ++mf)
#pragma unroll
    for (int nf = 0; nf < 2; ++nf) lg[mf][nf] = zero4();
  gemm32(S, Wg2_b, lane, c0, lg, b0g2);
  __syncthreads();                                   // #8 (all h2 reads done)

  // EARLY v-gather: L2 latency hides under the softmax below.
  bf16x8 vreg[4];
#pragma unroll
  for (int it = 0; it < 4; ++it)
    vreg[it] = *(const bf16x8*)(vtab + (bN + jrow[it])*DD + f0);

  // ---- phase 6: softmax over 64 rows per column -> w into S; op = Sigma w*pos ----
#pragma unroll
  for (int nf = 0; nf < 2; ++nf){
    float bias = (nf == 0) ? bg2lo : bg2hi;
    float m = -1e30f;
#pragma unroll
    for (int mf = 0; mf < 4; ++mf)
#pragma unroll
      for (int r = 0; r < 4; ++r){ lg[mf][nf][r] += bias; m = fmaxf(m, lg[mf][nf][r]); }
    m = fmaxf(m, __shfl_xor(m, 16));
    m = fmaxf(m, __shfl_xor(m, 32));
    float s = 0.f;
#pragma unroll
    for (int mf = 0; mf < 4; ++mf)
#pragma unroll
      for (int r = 0; r < 4; ++r){
        float e = __expf((lg[mf][nf][r] - m) * 0.0625f);
        lg[mf][nf][r] = e; s += e;
      }
    s += __shfl_xor(s, 16);
    s += __shfl_xor(s, 32);
    float inv = 1.f / s;
    float op = 0.f;
#pragma unroll
    for (int mf = 0; mf < 4; ++mf){
      int row = mf*16 + (lane >> 4)*4;
      int col = c0 + nf*16 + (lane & 15);
#pragma unroll
      for (int h = 0; h < 2; ++h){
        float w0 = lg[mf][nf][2*h]   * inv;
        float w1 = lg[mf][nf][2*h+1] * inv;
        op = fmaf(w0, b2f((unsigned short)(pos_pk[mf][nf][h] & 0xffff)), op);
        op = fmaf(w1, b2f((unsigned short)(pos_pk[mf][nf][h] >> 16)),   op);
        unsigned pk = f2b2(w0, w1);
        *(unsigned short*)(S + rof(row + 2*h,     col*2)) = (unsigned short)(pk & 0xffff);
        *(unsigned short*)(S + rof(row + 2*h + 1, col*2)) = (unsigned short)(pk >> 16);
      }
    }
    op += __shfl_xor(op, 16);
    op += __shfl_xor(op, 32);
    if (lane < 16) s_out[c0 + nf*16 + lane] = op;
  }
  __syncthreads();                                   // #9

  // ---- phase 7: Sigma_k w*v; partials alias into consumed S rows ----
  {
    float accv[8];
#pragma unroll
    for (int e = 0; e < 8; ++e) accv[e] = 0.f;
#pragma unroll
    for (int kk2 = 0; kk2 < 4; ++kk2){
      int row = gang*4 + kk2;
      bf16x8 w8 = *(const bf16x8*)(S + rof(row, f0*2));
#pragma unroll
      for (int e = 0; e < 8; ++e)
        accv[e] = fmaf(b2f((unsigned short)w8[e]), b2f((unsigned short)vreg[kk2][e]), accv[e]);
    }
    // gang's own 4 w-rows are consumed (wave-lockstep); 1KB partial per gang.
    float* red = (float*)(S + gang*4*PITCH);
    f32x4 lo = {accv[0], accv[1], accv[2], accv[3]};
    f32x4 hi = {accv[4], accv[5], accv[6], accv[7]};
    *(f32x4*)(red + f0)     = lo;
    *(f32x4*)(red + f0 + 4) = hi;
  }
  __syncthreads();                                   // #10
  if (tid < 256){
    float v = s_out[tid];
#pragma unroll
    for (int p = 0; p < 16; ++p) v += *(const float*)(S + p*4*PITCH + tid*4);
    long oi = ((long)b*GG + g)*DD + tid;
    if (flag) ((unsigned short*)out)[oi] = f2b(v);
    else      ((float*)out)[oi] = v;
  }
}

extern "C" void kernel_launch(void* const* d_in, const int* in_sizes, int n_in,
                              void* d_out, int out_size, void* d_ws, size_t ws_size,
                              hipStream_t stream){
  char* ws = (char*)d_ws;
  int* flag = (int*)ws;
  unsigned short* ktab = (unsigned short*)(ws + 256);
  unsigned short* vtab = ktab + (size_t)BB*NN*DD;
  float* gq   = (float*)(vtab + (size_t)BB*NN*DD);
  float* xyzf = gq + (size_t)BB*GG*DD;
  unsigned short* Wq_b  = (unsigned short*)(xyzf + (size_t)BB*NN*3);
  unsigned short* Wk_b  = Wq_b  + DD*DD;
  unsigned short* Wv_b  = Wk_b  + DD*DD;
  unsigned short* Wd2_b = Wv_b  + DD*DD;
  unsigned short* Wg1_b = Wd2_b + DD*DD;
  unsigned short* Wg2_b = Wg1_b + DD*DD;
  float* Wd1f = (float*)(Wg2_b + DD*DD);
  float* bd1f = Wd1f + DD*3;
  float* bd2f = bd1f + DD;
  float* bg1f = bd2f + DD;
  float* bg2f = bg1f + DD;

  k_detect<<<1, 64, 0, stream>>>((const unsigned short*)d_in[1], flag);

  PrepArgs P;
  const int wsrc[6] = {3, 4, 5, 8, 10, 12};   // Wq, Wk, Wv, Wd2, Wg1, Wg2
  unsigned short* wdst[6] = {Wq_b, Wk_b, Wv_b, Wd2_b, Wg1_b, Wg2_b};
  for (int i = 0; i < 6; ++i){ P.src[i] = d_in[wsrc[i]]; P.dst[i] = wdst[i]; P.n[i] = DD*DD; P.bf16out[i] = 1; }
  P.src[6]  = d_in[0];  P.dst[6]  = xyzf; P.n[6]  = BB*NN*3; P.bf16out[6]  = 0;
  P.src[7]  = d_in[6];  P.dst[7]  = Wd1f; P.n[7]  = DD*3;    P.bf16out[7]  = 0;
  P.src[8]  = d_in[7];  P.dst[8]  = bd1f; P.n[8]  = DD;      P.bf16out[8]  = 0;
  P.src[9]  = d_in[9];  P.dst[9]  = bd2f; P.n[9]  = DD;      P.bf16out[9]  = 0;
  P.src[10] = d_in[11]; P.dst[10] = bg1f; P.n[10] = DD;      P.bf16out[10] = 0;
  P.src[11] = d_in[13]; P.dst[11] = bg2f; P.n[11] = DD;      P.bf16out[11] = 0;
  k_prep<<<256, 256, 0, stream>>>(P, flag);

  k_gemmA<<<512, 256, 0, stream>>>(d_in[1], Wq_b, Wk_b, Wv_b, ktab, vtab, gq, flag);

  k_attn<<<4096, 512, 0, stream>>>(ktab, vtab, gq, xyzf, (const int*)d_in[2],
      Wd2_b, Wg1_b, Wg2_b, Wd1f, bd1f, bd2f, bg1f, bg2f, d_out, flag);
}

// Round 11
// 331.497 us; speedup vs baseline: 1.0488x; 1.0488x over previous
//
#include <hip/hip_runtime.h>

#define DEV static __device__ __forceinline__

typedef __attribute__((ext_vector_type(8))) short bf16x8;
typedef __attribute__((ext_vector_type(4))) float f32x4;
typedef __attribute__((ext_vector_type(4))) unsigned u32x4;

constexpr int BB = 8, NN = 4096, KK = 64, DD = 256, GG = 512;
constexpr int PITCH = 560;   // bytes/row: 140 dwords, rot 12 banks/row -> cheap conflicts, additive addressing

DEV unsigned short f2b(float f){
  unsigned u = __builtin_bit_cast(unsigned, f);
  unsigned r = (u + 0x7FFFu + ((u >> 16) & 1u)) >> 16;
  return (unsigned short)r;
}
DEV float b2f(unsigned short h){
  unsigned u = ((unsigned)h) << 16;
  return __builtin_bit_cast(float, u);
}
// 1-op packed f32x2 -> bf16x2 (RNE).
DEV unsigned f2b2(float lo, float hi){
  unsigned r;
  asm("v_cvt_pk_bf16_f32 %0, %1, %2" : "=v"(r) : "v"(lo), "v"(hi));
  return r;
}
DEV int rof(int row, int byteoff){ return row*PITCH + byteoff; }

DEV f32x4 zero4(){ f32x4 z = {0.f, 0.f, 0.f, 0.f}; return z; }

// ---------------- dtype detector ----------------
__global__ void k_detect(const unsigned short* __restrict__ x_raw, int* __restrict__ flag){
  int lane = threadIdx.x;  // 64 threads
  float mx = 0.f;
#pragma unroll
  for (int i = 0; i < 16; ++i) mx = fmaxf(mx, fabsf(b2f(x_raw[lane*16 + i])));
  unsigned long long big = __ballot(mx > 1e4f);
  if (lane == 0) *flag = (big == 0ull) ? 1 : 0;
}

// ---------------- conversion of weights / xyz / biases ----------------
struct PrepArgs {
  const void* src[12];
  void*       dst[12];
  int         n[12];
  int         bf16out[12];
};

__global__ void k_prep(PrepArgs P, const int* __restrict__ flagp){
  int flag = *flagp;
  long stride = (long)gridDim.x * blockDim.x;
  long gid = (long)blockIdx.x * blockDim.x + threadIdx.x;
  for (int s = 0; s < 12; ++s){
    int ns = P.n[s];
    const void* sp = P.src[s];
    if (P.bf16out[s]){
      unsigned short* dp = (unsigned short*)P.dst[s];
      for (long i = gid; i < ns; i += stride)
        dp[i] = flag ? ((const unsigned short*)sp)[i] : f2b(((const float*)sp)[i]);
    } else {
      float* dp = (float*)P.dst[s];
      for (long i = gid; i < ns; i += stride)
        dp[i] = flag ? b2f(((const unsigned short*)sp)[i]) : ((const float*)sp)[i];
    }
  }
}

// ---------------- 64x256 @ (64-col slice of W)^T, per-wave 64x64 (k_gemmA) ----------------
DEV void gemm64(const char* sbuf, const unsigned short* __restrict__ Wt,
                int lane, int c0, f32x4 acc[4][4]){
  const int lrow = lane & 15, lk = lane >> 4;
  const unsigned short* wbase = Wt + (c0 + lrow)*DD + lk*8;
  bf16x8 bcur[4], bnxt[4];
#pragma unroll
  for (int nf = 0; nf < 4; ++nf) bcur[nf] = *(const bf16x8*)(wbase + nf*16*DD);
#pragma unroll
  for (int ks = 0; ks < 8; ++ks){
    bf16x8 a[4];
#pragma unroll
    for (int mf = 0; mf < 4; ++mf)
      a[mf] = *(const bf16x8*)(sbuf + rof(mf*16 + lrow, ks*64 + lk*16));
    if (ks < 7){
#pragma unroll
      for (int nf = 0; nf < 4; ++nf)
        bnxt[nf] = *(const bf16x8*)(wbase + nf*16*DD + (ks + 1)*32);
    }
    __builtin_amdgcn_s_setprio(1);
#pragma unroll
    for (int mf = 0; mf < 4; ++mf)
#pragma unroll
      for (int nf = 0; nf < 4; ++nf)
        acc[mf][nf] = __builtin_amdgcn_mfma_f32_16x16x32_bf16(a[mf], bcur[nf], acc[mf][nf], 0, 0, 0);
    __builtin_amdgcn_s_setprio(0);
#pragma unroll
    for (int nf = 0; nf < 4; ++nf) bcur[nf] = bnxt[nf];
  }
}

// ---------------- 64x256 @ (32-col slice of W)^T, per-wave 64x32 (k_attn) ----------------
// Self-contained (no preB): minimal cross-phase register footprint for the
// 6-waves/SIMD target (<=85 regs incl. AGPRs).
DEV void gemm32(const char* sbuf, const unsigned short* __restrict__ Wt,
                int lane, int c0, f32x4 acc[4][2]){
  const int lrow = lane & 15, lk = lane >> 4;
  const unsigned short* wbase = Wt + (c0 + lrow)*DD + lk*8;
  bf16x8 bcur[2], bnxt[2];
#pragma unroll
  for (int nf = 0; nf < 2; ++nf) bcur[nf] = *(const bf16x8*)(wbase + nf*16*DD);
#pragma unroll
  for (int ks = 0; ks < 8; ++ks){
    bf16x8 a[4];
#pragma unroll
    for (int mf = 0; mf < 4; ++mf)
      a[mf] = *(const bf16x8*)(sbuf + rof(mf*16 + lrow, ks*64 + lk*16));
    if (ks < 7){
#pragma unroll
      for (int nf = 0; nf < 2; ++nf)
        bnxt[nf] = *(const bf16x8*)(wbase + nf*16*DD + (ks + 1)*32);
    }
    __builtin_amdgcn_s_setprio(1);
#pragma unroll
    for (int mf = 0; mf < 4; ++mf)
#pragma unroll
      for (int nf = 0; nf < 2; ++nf)
        acc[mf][nf] = __builtin_amdgcn_mfma_f32_16x16x32_bf16(a[mf], bcur[nf], acc[mf][nf], 0, 0, 0);
    __builtin_amdgcn_s_setprio(0);
#pragma unroll
    for (int nf = 0; nf < 2; ++nf) bcur[nf] = bnxt[nf];
  }
}

// ---------------- Phase A: k = x@Wk.T, v = x@Wv.T, gq = x[:, :G]@Wq.T ----------------
__global__ __launch_bounds__(256, 2) void k_gemmA(
    const void* __restrict__ x_in,
    const unsigned short* __restrict__ Wq_b, const unsigned short* __restrict__ Wk_b,
    const unsigned short* __restrict__ Wv_b,
    unsigned short* __restrict__ ktab, unsigned short* __restrict__ vtab,
    float* __restrict__ gq, const int* __restrict__ flagp){
  __shared__ __align__(16) char sA[64*PITCH];
  const int tid = threadIdx.x, lane = tid & 63, wv = tid >> 6;
  const int flag = *flagp;
  const long row0 = (long)blockIdx.x * 64;
  const int b = (int)(row0 >> 12), n0 = (int)(row0 & 4095);

#pragma unroll
  for (int it = 0; it < 8; ++it){
    int r = (tid >> 5) + it*8;
    int f0 = (tid & 31)*8;
    bf16x8 v;
    if (flag){
      v = *(const bf16x8*)((const unsigned short*)x_in + (row0 + r)*DD + f0);
    } else {
      const float* xp = (const float*)x_in + (row0 + r)*DD + f0;
      f32x4 lo = *(const f32x4*)xp;
      f32x4 hi = *(const f32x4*)(xp + 4);
      u32x4 t;
#pragma unroll
      for (int e = 0; e < 2; ++e){ t[e] = f2b2(lo[2*e], lo[2*e+1]); t[e+2] = f2b2(hi[2*e], hi[2*e+1]); }
      v = __builtin_bit_cast(bf16x8, t);
    }
    *(bf16x8*)(sA + rof(r, f0*2)) = v;
  }
  __syncthreads();

  const int c0 = wv*64;
  const int nout = (n0 < GG) ? 3 : 2;
  for (int o = 0; o < nout; ++o){
    const unsigned short* Wt = (o == 0) ? Wk_b : (o == 1) ? Wv_b : Wq_b;
    f32x4 acc[4][4];
#pragma unroll
    for (int mf = 0; mf < 4; ++mf)
#pragma unroll
      for (int nf = 0; nf < 4; ++nf) acc[mf][nf] = zero4();
    gemm64(sA, Wt, lane, c0, acc);
#pragma unroll
    for (int mf = 0; mf < 4; ++mf)
#pragma unroll
      for (int nf = 0; nf < 4; ++nf)
#pragma unroll
        for (int r = 0; r < 4; ++r){
          int grow = mf*16 + (lane >> 4)*4 + r;
          int col = c0 + nf*16 + (lane & 15);
          float v = acc[mf][nf][r];
          if (o == 0)      ktab[(row0 + grow)*DD + col] = f2b(v);
          else if (o == 1) vtab[(row0 + grow)*DD + col] = f2b(v);
          else             gq[((long)b*GG + n0 + grow)*DD + col] = v;
        }
  }
}

// ---------------- Phase B: fused per-group attention (512 threads / 8 waves) ----------------
// SINGLE LDS tile S (~38 KB). pos in packed bf16 regs (pos_pk). All other
// cross-GEMM register blocks eliminated (k, v loaded in their consuming phase;
// no B-prefetch) so peak live regs ~84 -> 3 WGs/CU = 24 waves = 66% occupancy.
__global__ __launch_bounds__(512, 6) void k_attn(
    const unsigned short* __restrict__ ktab, const unsigned short* __restrict__ vtab,
    const float* __restrict__ gq, const float* __restrict__ xyzf, const int* __restrict__ didx,
    const unsigned short* __restrict__ Wd2_b, const unsigned short* __restrict__ Wg1_b,
    const unsigned short* __restrict__ Wg2_b,
    const float* __restrict__ Wd1f, const float* __restrict__ bd1f, const float* __restrict__ bd2f,
    const float* __restrict__ bg1f, const float* __restrict__ bg2f,
    void* __restrict__ out, const int* __restrict__ flagp){
  __shared__ __align__(16) char S[64*PITCH];  // H1 -> pos -> a_in -> h2 -> w -> partials
  __shared__ float s_gq[256];
  __shared__ float s_delta[64*3];
  __shared__ float s_out[256];

  const int tid = threadIdx.x, lane = tid & 63, wv = tid >> 6;   // wv 0..7
  const int gang = tid >> 5;          // 0..15: rows gang*4 .. gang*4+3
  const int f0 = (tid & 31)*8;        // col start for row-phases
  const int flag = *flagp;
  int wg = blockIdx.x;
  wg = (wg & 7)*512 + (wg >> 3);      // XCD swizzle: batch-contiguous per XCD
  const int b = wg >> 9, g = wg & 511;
  const long bN = (long)b * NN;

  // ---- phase 0: indices, gq, delta; Wd1/bd1 -> registers; bg2 bias hoist ----
  int jrow[4];
  {
    const int* dptr = didx + (bN + g)*KK + gang*4;
#pragma unroll
    for (int it = 0; it < 4; ++it) jrow[it] = dptr[it];
  }
  if (tid < 256) s_gq[tid] = gq[((long)b*GG + g)*DD + tid];
  if (tid < 64){
    int j = didx[(bN + g)*KK + tid];
    long qb = (bN + g)*3, jb = (bN + j)*3;
#pragma unroll
    for (int c = 0; c < 3; ++c) s_delta[tid*3 + c] = xyzf[qb + c] - xyzf[jb + c];
  }
  f32x4 w1v[6];
  {
    const f32x4* wp = (const f32x4*)(Wd1f + f0*3);
#pragma unroll
    for (int q = 0; q < 6; ++q) w1v[q] = wp[q];
  }
  f32x4 b1lo = *(const f32x4*)(bd1f + f0), b1hi = *(const f32x4*)(bd1f + f0 + 4);
  const int c0 = wv*32;
  float bg2lo = bg2f[c0 + (lane & 15)];
  float bg2hi = bg2f[c0 + 16 + (lane & 15)];
  __syncthreads();                                   // #1

  // ---- phase 1: H1 = relu(delta @ Wd1.T + bd1) -> S ----
#pragma unroll
  for (int it = 0; it < 4; ++it){
    int r = gang*4 + it;
    float d0 = s_delta[r*3], d1 = s_delta[r*3+1], d2 = s_delta[r*3+2];
    float h[8];
#pragma unroll
    for (int e = 0; e < 8; ++e){
      float bias = (e < 4) ? b1lo[e] : b1hi[e-4];
      float w0 = w1v[(e*3+0) >> 2][(e*3+0) & 3];
      float w1 = w1v[(e*3+1) >> 2][(e*3+1) & 3];
      float w2 = w1v[(e*3+2) >> 2][(e*3+2) & 3];
      h[e] = fmaxf(fmaf(d0, w0, fmaf(d1, w1, fmaf(d2, w2, bias))), 0.f);
    }
    u32x4 t;
#pragma unroll
    for (int q = 0; q < 4; ++q) t[q] = f2b2(h[2*q], h[2*q+1]);
    *(bf16x8*)(S + rof(r, f0*2)) = __builtin_bit_cast(bf16x8, t);
  }
  __syncthreads();                                   // #2

  // ---- phase 2: pos = H1 @ Wd2.T + bd2 -> pos_pk regs AND bf16 into S ----
  unsigned pos_pk[4][2][2];
  {
    f32x4 acc[4][2];
#pragma unroll
    for (int mf = 0; mf < 4; ++mf)
#pragma unroll
      for (int nf = 0; nf < 2; ++nf) acc[mf][nf] = zero4();
    gemm32(S, Wd2_b, lane, c0, acc);
    __syncthreads();                                 // #3 (all H1 reads done before S overwrite)
#pragma unroll
    for (int nf = 0; nf < 2; ++nf){
      float bias = bd2f[c0 + nf*16 + (lane & 15)];
#pragma unroll
      for (int mf = 0; mf < 4; ++mf){
        int row = mf*16 + (lane >> 4)*4;
        int col = c0 + nf*16 + (lane & 15);
#pragma unroll
        for (int h = 0; h < 2; ++h){
          unsigned pk = f2b2(acc[mf][nf][2*h] + bias, acc[mf][nf][2*h+1] + bias);
          pos_pk[mf][nf][h] = pk;
          *(unsigned short*)(S + rof(row + 2*h,     col*2)) = (unsigned short)(pk & 0xffff);
          *(unsigned short*)(S + rof(row + 2*h + 1, col*2)) = (unsigned short)(pk >> 16);
        }
      }
    }
  }
  __syncthreads();                                   // #4 (pos visible)

  // ---- phase 3: a_in = gq - k + pos, IN PLACE in S (k loaded here, L2-hot) ----
  {
    bf16x8 kreg[4];
#pragma unroll
    for (int it = 0; it < 4; ++it)
      kreg[it] = *(const bf16x8*)(ktab + (bN + jrow[it])*DD + f0);
#pragma unroll
    for (int it = 0; it < 4; ++it){
      int r = gang*4 + it;
      bf16x8 p8 = *(const bf16x8*)(S + rof(r, f0*2));
      float v[8];
#pragma unroll
      for (int e = 0; e < 8; ++e)
        v[e] = s_gq[f0 + e] - b2f((unsigned short)kreg[it][e]) + b2f((unsigned short)p8[e]);
      u32x4 t;
#pragma unroll
      for (int q = 0; q < 4; ++q) t[q] = f2b2(v[2*q], v[2*q+1]);
      *(bf16x8*)(S + rof(r, f0*2)) = __builtin_bit_cast(bf16x8, t);
    }
  }
  __syncthreads();                                   // #5

  // ---- phase 4: h2 = relu(a_in @ Wg1.T + bg1) -> S ----
  {
    f32x4 acc[4][2];
#pragma unroll
    for (int mf = 0; mf < 4; ++mf)
#pragma unroll
      for (int nf = 0; nf < 2; ++nf) acc[mf][nf] = zero4();
    gemm32(S, Wg1_b, lane, c0, acc);
    __syncthreads();                                 // #6 (all a_in reads done)
#pragma unroll
    for (int nf = 0; nf < 2; ++nf){
      float bias = bg1f[c0 + nf*16 + (lane & 15)];
#pragma unroll
      for (int mf = 0; mf < 4; ++mf){
        int row = mf*16 + (lane >> 4)*4;
        int col = c0 + nf*16 + (lane & 15);
#pragma unroll
        for (int h = 0; h < 2; ++h){
          unsigned pk = f2b2(fmaxf(acc[mf][nf][2*h] + bias, 0.f),
                             fmaxf(acc[mf][nf][2*h+1] + bias, 0.f));
          *(unsigned short*)(S + rof(row + 2*h,     col*2)) = (unsigned short)(pk & 0xffff);
          *(unsigned short*)(S + rof(row + 2*h + 1, col*2)) = (unsigned short)(pk >> 16);
        }
      }
    }
  }
  __syncthreads();                                   // #7

  // ---- phase 5: logits = h2 @ Wg2.T + bg2 ----
  f32x4 lg[4][2];
#pragma unroll
  for (int mf = 0; mf < 4; ++mf)
#pragma unroll
    for (int nf = 0; nf < 2; ++nf) lg[mf][nf] = zero4();
  gemm32(S, Wg2_b, lane, c0, lg);
  __syncthreads();                                   // #8 (all h2 reads done)

  // ---- phase 6: softmax over 64 rows per column -> w into S; op = Sigma w*pos ----
#pragma unroll
  for (int nf = 0; nf < 2; ++nf){
    float bias = (nf == 0) ? bg2lo : bg2hi;
    float m = -1e30f;
#pragma unroll
    for (int mf = 0; mf < 4; ++mf)
#pragma unroll
      for (int r = 0; r < 4; ++r){ lg[mf][nf][r] += bias; m = fmaxf(m, lg[mf][nf][r]); }
    m = fmaxf(m, __shfl_xor(m, 16));
    m = fmaxf(m, __shfl_xor(m, 32));
    float s = 0.f;
#pragma unroll
    for (int mf = 0; mf < 4; ++mf)
#pragma unroll
      for (int r = 0; r < 4; ++r){
        float e = __expf((lg[mf][nf][r] - m) * 0.0625f);
        lg[mf][nf][r] = e; s += e;
      }
    s += __shfl_xor(s, 16);
    s += __shfl_xor(s, 32);
    float inv = 1.f / s;
    float op = 0.f;
#pragma unroll
    for (int mf = 0; mf < 4; ++mf){
      int row = mf*16 + (lane >> 4)*4;
      int col = c0 + nf*16 + (lane & 15);
#pragma unroll
      for (int h = 0; h < 2; ++h){
        float w0 = lg[mf][nf][2*h]   * inv;
        float w1 = lg[mf][nf][2*h+1] * inv;
        op = fmaf(w0, b2f((unsigned short)(pos_pk[mf][nf][h] & 0xffff)), op);
        op = fmaf(w1, b2f((unsigned short)(pos_pk[mf][nf][h] >> 16)),   op);
        unsigned pk = f2b2(w0, w1);
        *(unsigned short*)(S + rof(row + 2*h,     col*2)) = (unsigned short)(pk & 0xffff);
        *(unsigned short*)(S + rof(row + 2*h + 1, col*2)) = (unsigned short)(pk >> 16);
      }
    }
    op += __shfl_xor(op, 16);
    op += __shfl_xor(op, 32);
    if (lane < 16) s_out[c0 + nf*16 + lane] = op;
  }
  __syncthreads();                                   // #9

  // ---- phase 7: Sigma_k w*v (v loaded here, L2-hot); partials alias into S ----
  {
    bf16x8 vreg[4];
#pragma unroll
    for (int it = 0; it < 4; ++it)
      vreg[it] = *(const bf16x8*)(vtab + (bN + jrow[it])*DD + f0);
    float accv[8];
#pragma unroll
    for (int e = 0; e < 8; ++e) accv[e] = 0.f;
#pragma unroll
    for (int kk2 = 0; kk2 < 4; ++kk2){
      int row = gang*4 + kk2;
      bf16x8 w8 = *(const bf16x8*)(S + rof(row, f0*2));
#pragma unroll
      for (int e = 0; e < 8; ++e)
        accv[e] = fmaf(b2f((unsigned short)w8[e]), b2f((unsigned short)vreg[kk2][e]), accv[e]);
    }
    // gang's own 4 w-rows are consumed (wave-lockstep); 1KB partial per gang.
    float* red = (float*)(S + gang*4*PITCH);
    f32x4 lo = {accv[0], accv[1], accv[2], accv[3]};
    f32x4 hi = {accv[4], accv[5], accv[6], accv[7]};
    *(f32x4*)(red + f0)     = lo;
    *(f32x4*)(red + f0 + 4) = hi;
  }
  __syncthreads();                                   // #10
  if (tid < 256){
    float v = s_out[tid];
#pragma unroll
    for (int p = 0; p < 16; ++p) v += *(const float*)(S + p*4*PITCH + tid*4);
    long oi = ((long)b*GG + g)*DD + tid;
    if (flag) ((unsigned short*)out)[oi] = f2b(v);
    else      ((float*)out)[oi] = v;
  }
}

extern "C" void kernel_launch(void* const* d_in, const int* in_sizes, int n_in,
                              void* d_out, int out_size, void* d_ws, size_t ws_size,
                              hipStream_t stream){
  char* ws = (char*)d_ws;
  int* flag = (int*)ws;
  unsigned short* ktab = (unsigned short*)(ws + 256);
  unsigned short* vtab = ktab + (size_t)BB*NN*DD;
  float* gq   = (float*)(vtab + (size_t)BB*NN*DD);
  float* xyzf = gq + (size_t)BB*GG*DD;
  unsigned short* Wq_b  = (unsigned short*)(xyzf + (size_t)BB*NN*3);
  unsigned short* Wk_b  = Wq_b  + DD*DD;
  unsigned short* Wv_b  = Wk_b  + DD*DD;
  unsigned short* Wd2_b = Wv_b  + DD*DD;
  unsigned short* Wg1_b = Wd2_b + DD*DD;
  unsigned short* Wg2_b = Wg1_b + DD*DD;
  float* Wd1f = (float*)(Wg2_b + DD*DD);
  float* bd1f = Wd1f + DD*3;
  float* bd2f = bd1f + DD;
  float* bg1f = bd2f + DD;
  float* bg2f = bg1f + DD;

  k_detect<<<1, 64, 0, stream>>>((const unsigned short*)d_in[1], flag);

  PrepArgs P;
  const int wsrc[6] = {3, 4, 5, 8, 10, 12};   // Wq, Wk, Wv, Wd2, Wg1, Wg2
  unsigned short* wdst[6] = {Wq_b, Wk_b, Wv_b, Wd2_b, Wg1_b, Wg2_b};
  for (int i = 0; i < 6; ++i){ P.src[i] = d_in[wsrc[i]]; P.dst[i] = wdst[i]; P.n[i] = DD*DD; P.bf16out[i] = 1; }
  P.src[6]  = d_in[0];  P.dst[6]  = xyzf; P.n[6]  = BB*NN*3; P.bf16out[6]  = 0;
  P.src[7]  = d_in[6];  P.dst[7]  = Wd1f; P.n[7]  = DD*3;    P.bf16out[7]  = 0;
  P.src[8]  = d_in[7];  P.dst[8]  = bd1f; P.n[8]  = DD;      P.bf16out[8]  = 0;
  P.src[9]  = d_in[9];  P.dst[9]  = bd2f; P.n[9]  = DD;      P.bf16out[9]  = 0;
  P.src[10] = d_in[11]; P.dst[10] = bg1f; P.n[10] = DD;      P.bf16out[10] = 0;
  P.src[11] = d_in[13]; P.dst[11] = bg2f; P.n[11] = DD;      P.bf16out[11] = 0;
  k_prep<<<256, 256, 0, stream>>>(P, flag);

  k_gemmA<<<512, 256, 0, stream>>>(d_in[1], Wq_b, Wk_b, Wv_b, ktab, vtab, gq, flag);

  k_attn<<<4096, 512, 0, stream>>>(ktab, vtab, gq, xyzf, (const int*)d_in[2],
      Wd2_b, Wg1_b, Wg2_b, Wd1f, bd1f, bd2f, bg1f, bg2f, d_out, flag);
}

// Round 12
// 270.013 us; speedup vs baseline: 1.2876x; 1.2277x over previous
//
#include <hip/hip_runtime.h>

#define DEV static __device__ __forceinline__

typedef __attribute__((ext_vector_type(8))) short bf16x8;
typedef __attribute__((ext_vector_type(4))) float f32x4;
typedef __attribute__((ext_vector_type(4))) unsigned u32x4;

constexpr int BB = 8, NN = 4096, KK = 64, DD = 256, GG = 512;
constexpr int PITCH = 560;   // bytes/row: 140 dwords, rot 12 banks/row -> cheap conflicts, additive addressing

DEV unsigned short f2b(float f){
  unsigned u = __builtin_bit_cast(unsigned, f);
  unsigned r = (u + 0x7FFFu + ((u >> 16) & 1u)) >> 16;
  return (unsigned short)r;
}
DEV float b2f(unsigned short h){
  unsigned u = ((unsigned)h) << 16;
  return __builtin_bit_cast(float, u);
}
// 1-op packed f32x2 -> bf16x2 (RNE).
DEV unsigned f2b2(float lo, float hi){
  unsigned r;
  asm("v_cvt_pk_bf16_f32 %0, %1, %2" : "=v"(r) : "v"(lo), "v"(hi));
  return r;
}
DEV int rof(int row, int byteoff){ return row*PITCH + byteoff; }

DEV f32x4 zero4(){ f32x4 z = {0.f, 0.f, 0.f, 0.f}; return z; }

// ---------------- dtype detector ----------------
__global__ void k_detect(const unsigned short* __restrict__ x_raw, int* __restrict__ flag){
  int lane = threadIdx.x;  // 64 threads
  float mx = 0.f;
#pragma unroll
  for (int i = 0; i < 16; ++i) mx = fmaxf(mx, fabsf(b2f(x_raw[lane*16 + i])));
  unsigned long long big = __ballot(mx > 1e4f);
  if (lane == 0) *flag = (big == 0ull) ? 1 : 0;
}

// ---------------- conversion of weights / xyz / biases ----------------
struct PrepArgs {
  const void* src[12];
  void*       dst[12];
  int         n[12];
  int         bf16out[12];
};

__global__ void k_prep(PrepArgs P, const int* __restrict__ flagp){
  int flag = *flagp;
  long stride = (long)gridDim.x * blockDim.x;
  long gid = (long)blockIdx.x * blockDim.x + threadIdx.x;
  for (int s = 0; s < 12; ++s){
    int ns = P.n[s];
    const void* sp = P.src[s];
    if (P.bf16out[s]){
      unsigned short* dp = (unsigned short*)P.dst[s];
      for (long i = gid; i < ns; i += stride)
        dp[i] = flag ? ((const unsigned short*)sp)[i] : f2b(((const float*)sp)[i]);
    } else {
      float* dp = (float*)P.dst[s];
      for (long i = gid; i < ns; i += stride)
        dp[i] = flag ? b2f(((const unsigned short*)sp)[i]) : ((const float*)sp)[i];
    }
  }
}

// Preload the first B-fragment pair of a 32-col GEMM.
DEV void preB(const unsigned short* __restrict__ Wt, int lane, int c0, bf16x8 b0[2]){
  const unsigned short* wbase = Wt + (c0 + (lane & 15))*DD + (lane >> 4)*8;
  b0[0] = *(const bf16x8*)(wbase);
  b0[1] = *(const bf16x8*)(wbase + 16*DD);
}

// ---------------- 64x256 @ (64-col slice of W)^T, per-wave 64x64 (k_gemmA) ----------------
DEV void gemm64(const char* sbuf, const unsigned short* __restrict__ Wt,
                int lane, int c0, f32x4 acc[4][4]){
  const int lrow = lane & 15, lk = lane >> 4;
  const unsigned short* wbase = Wt + (c0 + lrow)*DD + lk*8;
  bf16x8 bcur[4], bnxt[4];
#pragma unroll
  for (int nf = 0; nf < 4; ++nf) bcur[nf] = *(const bf16x8*)(wbase + nf*16*DD);
#pragma unroll
  for (int ks = 0; ks < 8; ++ks){
    bf16x8 a[4];
#pragma unroll
    for (int mf = 0; mf < 4; ++mf)
      a[mf] = *(const bf16x8*)(sbuf + rof(mf*16 + lrow, ks*64 + lk*16));
    if (ks < 7){
#pragma unroll
      for (int nf = 0; nf < 4; ++nf)
        bnxt[nf] = *(const bf16x8*)(wbase + nf*16*DD + (ks + 1)*32);
    }
    __builtin_amdgcn_s_setprio(1);
#pragma unroll
    for (int mf = 0; mf < 4; ++mf)
#pragma unroll
      for (int nf = 0; nf < 4; ++nf)
        acc[mf][nf] = __builtin_amdgcn_mfma_f32_16x16x32_bf16(a[mf], bcur[nf], acc[mf][nf], 0, 0, 0);
    __builtin_amdgcn_s_setprio(0);
#pragma unroll
    for (int nf = 0; nf < 4; ++nf) bcur[nf] = bnxt[nf];
  }
}

// ---------------- 64x256 @ (32-col slice of W)^T, per-wave 64x32 (k_attn) ----------------
// b0 = preloaded first B-fragments (see preB).
DEV void gemm32(const char* sbuf, const unsigned short* __restrict__ Wt,
                int lane, int c0, f32x4 acc[4][2], const bf16x8 b0[2]){
  const int lrow = lane & 15, lk = lane >> 4;
  const unsigned short* wbase = Wt + (c0 + lrow)*DD + lk*8;
  bf16x8 bcur[2], bnxt[2];
  bcur[0] = b0[0]; bcur[1] = b0[1];
#pragma unroll
  for (int ks = 0; ks < 8; ++ks){
    bf16x8 a[4];
#pragma unroll
    for (int mf = 0; mf < 4; ++mf)
      a[mf] = *(const bf16x8*)(sbuf + rof(mf*16 + lrow, ks*64 + lk*16));
    if (ks < 7){
#pragma unroll
      for (int nf = 0; nf < 2; ++nf)
        bnxt[nf] = *(const bf16x8*)(wbase + nf*16*DD + (ks + 1)*32);
    }
    __builtin_amdgcn_s_setprio(1);
#pragma unroll
    for (int mf = 0; mf < 4; ++mf)
#pragma unroll
      for (int nf = 0; nf < 2; ++nf)
        acc[mf][nf] = __builtin_amdgcn_mfma_f32_16x16x32_bf16(a[mf], bcur[nf], acc[mf][nf], 0, 0, 0);
    __builtin_amdgcn_s_setprio(0);
#pragma unroll
    for (int nf = 0; nf < 2; ++nf) bcur[nf] = bnxt[nf];
  }
}

// ---------------- Phase A: k = x@Wk.T, v = x@Wv.T, gq = x[:, :G]@Wq.T ----------------
__global__ __launch_bounds__(256, 2) void k_gemmA(
    const void* __restrict__ x_in,
    const unsigned short* __restrict__ Wq_b, const unsigned short* __restrict__ Wk_b,
    const unsigned short* __restrict__ Wv_b,
    unsigned short* __restrict__ ktab, unsigned short* __restrict__ vtab,
    float* __restrict__ gq, const int* __restrict__ flagp){
  __shared__ __align__(16) char sA[64*PITCH];
  const int tid = threadIdx.x, lane = tid & 63, wv = tid >> 6;
  const int flag = *flagp;
  const long row0 = (long)blockIdx.x * 64;
  const int b = (int)(row0 >> 12), n0 = (int)(row0 & 4095);

#pragma unroll
  for (int it = 0; it < 8; ++it){
    int r = (tid >> 5) + it*8;
    int f0 = (tid & 31)*8;
    bf16x8 v;
    if (flag){
      v = *(const bf16x8*)((const unsigned short*)x_in + (row0 + r)*DD + f0);
    } else {
      const float* xp = (const float*)x_in + (row0 + r)*DD + f0;
      f32x4 lo = *(const f32x4*)xp;
      f32x4 hi = *(const f32x4*)(xp + 4);
      u32x4 t;
#pragma unroll
      for (int e = 0; e < 2; ++e){ t[e] = f2b2(lo[2*e], lo[2*e+1]); t[e+2] = f2b2(hi[2*e], hi[2*e+1]); }
      v = __builtin_bit_cast(bf16x8, t);
    }
    *(bf16x8*)(sA + rof(r, f0*2)) = v;
  }
  __syncthreads();

  const int c0 = wv*64;
  const int nout = (n0 < GG) ? 3 : 2;
  for (int o = 0; o < nout; ++o){
    const unsigned short* Wt = (o == 0) ? Wk_b : (o == 1) ? Wv_b : Wq_b;
    f32x4 acc[4][4];
#pragma unroll
    for (int mf = 0; mf < 4; ++mf)
#pragma unroll
      for (int nf = 0; nf < 4; ++nf) acc[mf][nf] = zero4();
    gemm64(sA, Wt, lane, c0, acc);
#pragma unroll
    for (int mf = 0; mf < 4; ++mf)
#pragma unroll
      for (int nf = 0; nf < 4; ++nf)
#pragma unroll
        for (int r = 0; r < 4; ++r){
          int grow = mf*16 + (lane >> 4)*4 + r;
          int col = c0 + nf*16 + (lane & 15);
          float v = acc[mf][nf][r];
          if (o == 0)      ktab[(row0 + grow)*DD + col] = f2b(v);
          else if (o == 1) vtab[(row0 + grow)*DD + col] = f2b(v);
          else             gq[((long)b*GG + n0 + grow)*DD + col] = v;
        }
  }
}

// ---------------- Phase B: fused per-group attention (512 threads / 8 waves) ----------------
// Round-9 champion configuration: per-wave 64x32 slice; pos in LDS (U); Wd1/bd1
// in registers (die before first GEMM); padded-pitch LDS addressing; first
// B-fragments prefetched per GEMM; early k- and v-gathers. (512,4): 2 WG/CU,
// 16 waves, no spill. 3 WG/CU proven infeasible (r10/r11: spill at 85-reg cap).
__global__ __launch_bounds__(512, 4) void k_attn(
    const unsigned short* __restrict__ ktab, const unsigned short* __restrict__ vtab,
    const float* __restrict__ gq, const float* __restrict__ xyzf, const int* __restrict__ didx,
    const unsigned short* __restrict__ Wd2_b, const unsigned short* __restrict__ Wg1_b,
    const unsigned short* __restrict__ Wg2_b,
    const float* __restrict__ Wd1f, const float* __restrict__ bd1f, const float* __restrict__ bd2f,
    const float* __restrict__ bg1f, const float* __restrict__ bg2f,
    void* __restrict__ out, const int* __restrict__ flagp){
  __shared__ __align__(16) char S[64*PITCH];    // H1 -> a_in -> h2 -> w -> (aliased) partials
  __shared__ __align__(16) char U[64*PITCH];    // pos (bf16), live phases 2..7
  __shared__ float s_gq[256];
  __shared__ float s_delta[64*3];

  const int tid = threadIdx.x, lane = tid & 63, wv = tid >> 6;   // wv 0..7
  const int gang = tid >> 5;          // 0..15: rows gang*4 .. gang*4+3
  const int f0 = (tid & 31)*8;        // col start for row-phases
  const int flag = *flagp;
  int wg = blockIdx.x;
  wg = (wg & 7)*512 + (wg >> 3);      // XCD swizzle: batch-contiguous per XCD
  const int b = wg >> 9, g = wg & 511;
  const long bN = (long)b * NN;

  // ---- phase 0: indices, gq, delta; Wd1/bd1 -> registers; bg2 bias hoist ----
  int jrow[4];
  {
    const int* dptr = didx + (bN + g)*KK + gang*4;
#pragma unroll
    for (int it = 0; it < 4; ++it) jrow[it] = dptr[it];
  }
  if (tid < 256) s_gq[tid] = gq[((long)b*GG + g)*DD + tid];
  if (tid < 64){
    int j = didx[(bN + g)*KK + tid];
    long qb = (bN + g)*3, jb = (bN + j)*3;
#pragma unroll
    for (int c = 0; c < 3; ++c) s_delta[tid*3 + c] = xyzf[qb + c] - xyzf[jb + c];
  }
  f32x4 w1v[6];
  {
    const f32x4* wp = (const f32x4*)(Wd1f + f0*3);
#pragma unroll
    for (int q = 0; q < 6; ++q) w1v[q] = wp[q];
  }
  f32x4 b1lo = *(const f32x4*)(bd1f + f0), b1hi = *(const f32x4*)(bd1f + f0 + 4);
  const int c0 = wv*32;
  // phase-6 bias hoist (keeps the softmax from draining vmcnt behind early-v)
  float bg2lo = bg2f[c0 + (lane & 15)];
  float bg2hi = bg2f[c0 + 16 + (lane & 15)];
  __syncthreads();                                   // #1

  // ---- phase 1: H1 = relu(delta @ Wd1.T + bd1) -> S ----
  // Prefetch GEMM1b's first B-frags FIRST so its vmcnt-wait leaves kreg in flight.
  bf16x8 b0d2[2];
  preB(Wd2_b, lane, c0, b0d2);
#pragma unroll
  for (int it = 0; it < 4; ++it){
    int r = gang*4 + it;
    float d0 = s_delta[r*3], d1 = s_delta[r*3+1], d2 = s_delta[r*3+2];
    float h[8];
#pragma unroll
    for (int e = 0; e < 8; ++e){
      float bias = (e < 4) ? b1lo[e] : b1hi[e-4];
      float w0 = w1v[(e*3+0) >> 2][(e*3+0) & 3];
      float w1 = w1v[(e*3+1) >> 2][(e*3+1) & 3];
      float w2 = w1v[(e*3+2) >> 2][(e*3+2) & 3];
      h[e] = fmaxf(fmaf(d0, w0, fmaf(d1, w1, fmaf(d2, w2, bias))), 0.f);
    }
    u32x4 t;
#pragma unroll
    for (int q = 0; q < 4; ++q) t[q] = f2b2(h[2*q], h[2*q+1]);
    *(bf16x8*)(S + rof(r, f0*2)) = __builtin_bit_cast(bf16x8, t);
  }

  // EARLY k-gather: issue now, in flight through GEMM1b, consumed in phase 3.
  bf16x8 kreg[4];
#pragma unroll
  for (int it = 0; it < 4; ++it)
    kreg[it] = *(const bf16x8*)(ktab + (bN + jrow[it])*DD + f0);
  __syncthreads();                                   // #2

  // ---- phase 2: pos = H1 @ Wd2.T + bd2 -> U (bf16, C-layout writes) ----
  {
    f32x4 acc[4][2];
#pragma unroll
    for (int mf = 0; mf < 4; ++mf)
#pragma unroll
      for (int nf = 0; nf < 2; ++nf) acc[mf][nf] = zero4();
    gemm32(S, Wd2_b, lane, c0, acc, b0d2);
#pragma unroll
    for (int nf = 0; nf < 2; ++nf){
      float bias = bd2f[c0 + nf*16 + (lane & 15)];
#pragma unroll
      for (int mf = 0; mf < 4; ++mf){
        int row = mf*16 + (lane >> 4)*4;
        int col = c0 + nf*16 + (lane & 15);
#pragma unroll
        for (int h = 0; h < 2; ++h){
          unsigned pk = f2b2(acc[mf][nf][2*h] + bias, acc[mf][nf][2*h+1] + bias);
          *(unsigned short*)(U + rof(row + 2*h,     col*2)) = (unsigned short)(pk & 0xffff);
          *(unsigned short*)(U + rof(row + 2*h + 1, col*2)) = (unsigned short)(pk >> 16);
        }
      }
    }
  }
  __syncthreads();                                   // #3 (H1 reads done; pos visible)

  // ---- phase 3: a_in = gq - k + pos -> S (over H1); prefetch Wg1 b0 ----
  bf16x8 b0g1[2];
  preB(Wg1_b, lane, c0, b0g1);
#pragma unroll
  for (int it = 0; it < 4; ++it){
    int r = gang*4 + it;
    bf16x8 p8 = *(const bf16x8*)(U + rof(r, f0*2));
    float v[8];
#pragma unroll
    for (int e = 0; e < 8; ++e)
      v[e] = s_gq[f0 + e] - b2f((unsigned short)kreg[it][e]) + b2f((unsigned short)p8[e]);
    u32x4 t;
#pragma unroll
    for (int q = 0; q < 4; ++q) t[q] = f2b2(v[2*q], v[2*q+1]);
    *(bf16x8*)(S + rof(r, f0*2)) = __builtin_bit_cast(bf16x8, t);
  }
  __syncthreads();                                   // #4

  // ---- phase 4: h2 = relu(a_in @ Wg1.T + bg1) -> S; prefetch Wg2 b0 ----
  bf16x8 b0g2[2];
  {
    f32x4 acc[4][2];
#pragma unroll
    for (int mf = 0; mf < 4; ++mf)
#pragma unroll
      for (int nf = 0; nf < 2; ++nf) acc[mf][nf] = zero4();
    gemm32(S, Wg1_b, lane, c0, acc, b0g1);
    preB(Wg2_b, lane, c0, b0g2);
    __syncthreads();                                 // #5 (all a_in reads done)
#pragma unroll
    for (int nf = 0; nf < 2; ++nf){
      float bias = bg1f[c0 + nf*16 + (lane & 15)];
#pragma unroll
      for (int mf = 0; mf < 4; ++mf){
        int row = mf*16 + (lane >> 4)*4;
        int col = c0 + nf*16 + (lane & 15);
#pragma unroll
        for (int h = 0; h < 2; ++h){
          unsigned pk = f2b2(fmaxf(acc[mf][nf][2*h] + bias, 0.f),
                             fmaxf(acc[mf][nf][2*h+1] + bias, 0.f));
          *(unsigned short*)(S + rof(row + 2*h,     col*2)) = (unsigned short)(pk & 0xffff);
          *(unsigned short*)(S + rof(row + 2*h + 1, col*2)) = (unsigned short)(pk >> 16);
        }
      }
    }
  }
  __syncthreads();                                   // #6

  // ---- phase 5: logits = h2 @ Wg2.T + bg2 ----
  f32x4 lg[4][2];
#pragma unroll
  for (int mf = 0; mf < 4; ++mf)
#pragma unroll
    for (int nf = 0; nf < 2; ++nf) lg[mf][nf] = zero4();
  gemm32(S, Wg2_b, lane, c0, lg, b0g2);
  __syncthreads();                                   // #7 (all h2 reads done)

  // EARLY v-gather (T14): issue now; L2 latency hides under the softmax below.
  bf16x8 vreg[4];
#pragma unroll
  for (int it = 0; it < 4; ++it)
    vreg[it] = *(const bf16x8*)(vtab + (bN + jrow[it])*DD + f0);

  // ---- phase 6: softmax over 64 rows per column -> w into S ----
#pragma unroll
  for (int nf = 0; nf < 2; ++nf){
    float bias = (nf == 0) ? bg2lo : bg2hi;
    float m = -1e30f;
#pragma unroll
    for (int mf = 0; mf < 4; ++mf)
#pragma unroll
      for (int r = 0; r < 4; ++r){ lg[mf][nf][r] += bias; m = fmaxf(m, lg[mf][nf][r]); }
    m = fmaxf(m, __shfl_xor(m, 16));
    m = fmaxf(m, __shfl_xor(m, 32));
    float s = 0.f;
#pragma unroll
    for (int mf = 0; mf < 4; ++mf)
#pragma unroll
      for (int r = 0; r < 4; ++r){
        float e = __expf((lg[mf][nf][r] - m) * 0.0625f);
        lg[mf][nf][r] = e; s += e;
      }
    s += __shfl_xor(s, 16);
    s += __shfl_xor(s, 32);
    float inv = 1.f / s;
#pragma unroll
    for (int mf = 0; mf < 4; ++mf){
      int row = mf*16 + (lane >> 4)*4;
      int col = c0 + nf*16 + (lane & 15);
#pragma unroll
      for (int h = 0; h < 2; ++h){
        unsigned pk = f2b2(lg[mf][nf][2*h] * inv, lg[mf][nf][2*h+1] * inv);
        *(unsigned short*)(S + rof(row + 2*h,     col*2)) = (unsigned short)(pk & 0xffff);
        *(unsigned short*)(S + rof(row + 2*h + 1, col*2)) = (unsigned short)(pk >> 16);
      }
    }
  }
  __syncthreads();                                   // #8

  // ---- phase 7: Σ_k w*(v + pos); v already in regs; partials alias into S ----
  {
    float accv[8];
#pragma unroll
    for (int e = 0; e < 8; ++e) accv[e] = 0.f;
#pragma unroll
    for (int kk2 = 0; kk2 < 4; ++kk2){
      int row = gang*4 + kk2;
      bf16x8 w8 = *(const bf16x8*)(S + rof(row, f0*2));
      bf16x8 p8 = *(const bf16x8*)(U + rof(row, f0*2));
#pragma unroll
      for (int e = 0; e < 8; ++e)
        accv[e] = fmaf(b2f((unsigned short)w8[e]),
                       b2f((unsigned short)vreg[kk2][e]) + b2f((unsigned short)p8[e]), accv[e]);
    }
    // gang's own 4 w-rows are consumed (wave-lockstep: both gangs of this wave
    // finished their reads above); write 1KB partial into row gang*4 region.
    float* red = (float*)(S + gang*4*PITCH);
    f32x4 lo = {accv[0], accv[1], accv[2], accv[3]};
    f32x4 hi = {accv[4], accv[5], accv[6], accv[7]};
    *(f32x4*)(red + f0)     = lo;
    *(f32x4*)(red + f0 + 4) = hi;
  }
  __syncthreads();                                   // #9
  if (tid < 256){
    float v = 0.f;
#pragma unroll
    for (int p = 0; p < 16; ++p) v += *(const float*)(S + p*4*PITCH + tid*4);
    long oi = ((long)b*GG + g)*DD + tid;
    if (flag) ((unsigned short*)out)[oi] = f2b(v);
    else      ((float*)out)[oi] = v;
  }
}

extern "C" void kernel_launch(void* const* d_in, const int* in_sizes, int n_in,
                              void* d_out, int out_size, void* d_ws, size_t ws_size,
                              hipStream_t stream){
  char* ws = (char*)d_ws;
  int* flag = (int*)ws;
  unsigned short* ktab = (unsigned short*)(ws + 256);
  unsigned short* vtab = ktab + (size_t)BB*NN*DD;
  float* gq   = (float*)(vtab + (size_t)BB*NN*DD);
  float* xyzf = gq + (size_t)BB*GG*DD;
  unsigned short* Wq_b  = (unsigned short*)(xyzf + (size_t)BB*NN*3);
  unsigned short* Wk_b  = Wq_b  + DD*DD;
  unsigned short* Wv_b  = Wk_b  + DD*DD;
  unsigned short* Wd2_b = Wv_b  + DD*DD;
  unsigned short* Wg1_b = Wd2_b + DD*DD;
  unsigned short* Wg2_b = Wg1_b + DD*DD;
  float* Wd1f = (float*)(Wg2_b + DD*DD);
  float* bd1f = Wd1f + DD*3;
  float* bd2f = bd1f + DD;
  float* bg1f = bd2f + DD;
  float* bg2f = bg1f + DD;

  k_detect<<<1, 64, 0, stream>>>((const unsigned short*)d_in[1], flag);

  PrepArgs P;
  const int wsrc[6] = {3, 4, 5, 8, 10, 12};   // Wq, Wk, Wv, Wd2, Wg1, Wg2
  unsigned short* wdst[6] = {Wq_b, Wk_b, Wv_b, Wd2_b, Wg1_b, Wg2_b};
  for (int i = 0; i < 6; ++i){ P.src[i] = d_in[wsrc[i]]; P.dst[i] = wdst[i]; P.n[i] = DD*DD; P.bf16out[i] = 1; }
  P.src[6]  = d_in[0];  P.dst[6]  = xyzf; P.n[6]  = BB*NN*3; P.bf16out[6]  = 0;
  P.src[7]  = d_in[6];  P.dst[7]  = Wd1f; P.n[7]  = DD*3;    P.bf16out[7]  = 0;
  P.src[8]  = d_in[7];  P.dst[8]  = bd1f; P.n[8]  = DD;      P.bf16out[8]  = 0;
  P.src[9]  = d_in[9];  P.dst[9]  = bd2f; P.n[9]  = DD;      P.bf16out[9]  = 0;
  P.src[10] = d_in[11]; P.dst[10] = bg1f; P.n[10] = DD;      P.bf16out[10] = 0;
  P.src[11] = d_in[13]; P.dst[11] = bg2f; P.n[11] = DD;      P.bf16out[11] = 0;
  k_prep<<<256, 256, 0, stream>>>(P, flag);

  k_gemmA<<<512, 256, 0, stream>>>(d_in[1], Wq_b, Wk_b, Wv_b, ktab, vtab, gq, flag);

  k_attn<<<4096, 512, 0, stream>>>(ktab, vtab, gq, xyzf, (const int*)d_in[2],
      Wd2_b, Wg1_b, Wg2_b, Wd1f, bd1f, bd2f, bg1f, bg2f, d_out, flag);
}